// Round 11
// baseline (1967.704 us; speedup 1.0000x reference)
//
#include <hip/hip_runtime.h>
#include <hip/hip_fp16.h>

typedef _Float16 f16;
typedef _Float16 half8 __attribute__((ext_vector_type(8)));
typedef _Float16 half4 __attribute__((ext_vector_type(4)));
typedef float f32x4_t __attribute__((ext_vector_type(4)));
typedef unsigned int uint;
typedef unsigned int uint32x4 __attribute__((ext_vector_type(4)));

#define IN_DIM 512
#define H_DIM 1024
#define OUT_DIM 512
#define NBATCH 64
#define NSEQ 512
#define NGROUP 4
#define MB 16      // batch rows per group
#define WPG 16     // workgroups per group (j-split)
#define NJ 64      // j columns per workgroup
#define RING 4     // h ring depth (WG skew within a group <= 1 step)

// ---------------- f32 -> f16 conversion ----------------
__global__ __launch_bounds__(256) void cvt_f32_f16_k(const float* __restrict__ src,
                                                     f16* __restrict__ dst, int n) {
  int i = (blockIdx.x * 256 + threadIdx.x) * 4;
  if (i + 3 < n) {
    float4 v = *(const float4*)(src + i);
    half4 h;
    h[0] = (f16)v.x; h[1] = (f16)v.y; h[2] = (f16)v.z; h[3] = (f16)v.w;
    *(half4*)(dst + i) = h;
  }
}

__global__ __launch_bounds__(256) void bias_sum_k(const float* __restrict__ a,
                                                  const float* __restrict__ b,
                                                  float* __restrict__ o) {
  int i = blockIdx.x * 256 + threadIdx.x;
  if (i < H_DIM) o[i] = a[i] + b[i];
}

// fill hbuf ring with a pattern that is epoch-invalid for BOTH parities
// (low-half LSB=0, high-half LSB=1 -> never produced by real stores)
__global__ __launch_bounds__(256) void fill_pat_k(uint32x4* __restrict__ p, int n4) {
  int i = blockIdx.x * 256 + threadIdx.x;
  uint32x4 v;
  v[0] = 0x0001FFFEu; v[1] = 0x0001FFFEu; v[2] = 0x0001FFFEu; v[3] = 0x0001FFFEu;
  if (i < n4) p[i] = v;
}

// ---------------- xp = x @ W_ih^T + (b_ih + b_hh), stored [S][B][H] f16 ----------------
__global__ __launch_bounds__(256) void xp_gemm_k(
    const float* __restrict__ x, const float* __restrict__ wih,
    const float* __restrict__ bsum, f16* __restrict__ xp2)
{
  __shared__ f16 Alds[128 * 32];
  __shared__ f16 Blds[128 * 32];
  const int tid = threadIdx.x;
  const int l = tid & 63;
  const int w = tid >> 6;
  const int r0 = blockIdx.x * 128;
  const int n0 = blockIdx.y * 128;
  const int wm = (w >> 1) << 6;
  const int wn = (w & 1) << 6;
  const int srow = tid >> 1;
  const int scol = (tid & 1) << 4;
  const float* ax = x   + (size_t)(r0 + srow) * IN_DIM + scol;
  const float* bw = wih + (size_t)(n0 + srow) * IN_DIM + scol;
  const uint swz  = (uint)(srow & 7) << 4;
  const uint soff = (uint)srow * 64 + (uint)(tid & 1) * 32;
  char* Ab = (char*)Alds;
  char* Bb = (char*)Blds;

  f32x4_t acc[4][4];
  f32x4_t zv; zv[0] = 0.f; zv[1] = 0.f; zv[2] = 0.f; zv[3] = 0.f;
#pragma unroll
  for (int i = 0; i < 4; ++i)
#pragma unroll
    for (int j = 0; j < 4; ++j) acc[i][j] = zv;

  for (int k0 = 0; k0 < IN_DIM; k0 += 32) {
    float4 a0 = *(const float4*)(ax + k0);
    float4 a1 = *(const float4*)(ax + k0 + 4);
    float4 a2 = *(const float4*)(ax + k0 + 8);
    float4 a3 = *(const float4*)(ax + k0 + 12);
    float4 c0 = *(const float4*)(bw + k0);
    float4 c1 = *(const float4*)(bw + k0 + 4);
    float4 c2 = *(const float4*)(bw + k0 + 8);
    float4 c3 = *(const float4*)(bw + k0 + 12);
    __syncthreads();
    half8 pa0, pa1, pb0, pb1;
    pa0[0]=(f16)a0.x; pa0[1]=(f16)a0.y; pa0[2]=(f16)a0.z; pa0[3]=(f16)a0.w;
    pa0[4]=(f16)a1.x; pa0[5]=(f16)a1.y; pa0[6]=(f16)a1.z; pa0[7]=(f16)a1.w;
    pa1[0]=(f16)a2.x; pa1[1]=(f16)a2.y; pa1[2]=(f16)a2.z; pa1[3]=(f16)a2.w;
    pa1[4]=(f16)a3.x; pa1[5]=(f16)a3.y; pa1[6]=(f16)a3.z; pa1[7]=(f16)a3.w;
    pb0[0]=(f16)c0.x; pb0[1]=(f16)c0.y; pb0[2]=(f16)c0.z; pb0[3]=(f16)c0.w;
    pb0[4]=(f16)c1.x; pb0[5]=(f16)c1.y; pb0[6]=(f16)c1.z; pb0[7]=(f16)c1.w;
    pb1[0]=(f16)c2.x; pb1[1]=(f16)c2.y; pb1[2]=(f16)c2.z; pb1[3]=(f16)c2.w;
    pb1[4]=(f16)c3.x; pb1[5]=(f16)c3.y; pb1[6]=(f16)c3.z; pb1[7]=(f16)c3.w;
    *(half8*)(Ab + (soff ^ swz)) = pa0;
    *(half8*)(Ab + ((soff + 16) ^ swz)) = pa1;
    *(half8*)(Bb + (soff ^ swz)) = pb0;
    *(half8*)(Bb + ((soff + 16) ^ swz)) = pb1;
    __syncthreads();
    half8 af[4], bf[4];
#pragma unroll
    for (int mt = 0; mt < 4; ++mt) {
      uint rr = (uint)(wm + mt * 16 + (l & 15));
      uint off = rr * 64 + ((uint)(l >> 4) << 4);
      af[mt] = *(const half8*)(Ab + (off ^ ((rr & 7) << 4)));
    }
#pragma unroll
    for (int nt = 0; nt < 4; ++nt) {
      uint rr = (uint)(wn + nt * 16 + (l & 15));
      uint off = rr * 64 + ((uint)(l >> 4) << 4);
      bf[nt] = *(const half8*)(Bb + (off ^ ((rr & 7) << 4)));
    }
#pragma unroll
    for (int mt = 0; mt < 4; ++mt)
#pragma unroll
      for (int nt = 0; nt < 4; ++nt)
        acc[mt][nt] = __builtin_amdgcn_mfma_f32_16x16x32_f16(af[mt], bf[nt], acc[mt][nt], 0, 0, 0);
  }

#pragma unroll
  for (int nt = 0; nt < 4; ++nt) {
    const int n = n0 + wn + nt * 16 + (l & 15);
    const float bv = bsum[n];
#pragma unroll
    for (int mt = 0; mt < 4; ++mt) {
#pragma unroll
      for (int i = 0; i < 4; ++i) {
        int r = r0 + wm + mt * 16 + ((l >> 4) << 2) + i;
        int s = r & (NSEQ - 1);
        int b = r >> 9;
        xp2[((size_t)s * NBATCH + b) * H_DIM + n] = (f16)(acc[mt][nt][i] + bv);
      }
    }
  }
}

// ---------------- persistent recurrent scan (r8 protocol, hardened + probe pre-issue) ----------------
// 64 WGs = 4 groups x 16 j-slices. K-split: wave w holds W[64j x 256k] f16 in
// 128 pinned regs, pulls its 512B h A-fragment per step from L3 (sc0 sc1).
// Data self-validates via per-f16 epoch LSB (parity of t>>2); producers store
// relaxed agent-atomics, never wait. Spin protocol = r8-proven: every check is
// preceded by a FULL s_waitcnt vmcnt(0) drain (no counted waits anywhere).
// Hardening vs r8: all spin loads use "=&v" (early clobber) so no async load
// output can alias the live address pair (the r9/r10 corruption mechanism).
// New overlap: the first probe batch for step t+1 is pre-issued at the END of
// step t (right after the h-store; sv is dead there) -> its RTT overlaps the
// loop tail and the peers' store-landing window; the next spin starts with
// drain+check instead of issue+drain+check.
__global__ __launch_bounds__(256, 1) void rnn_scan_k(
    const f16* __restrict__ whh2, const f16* __restrict__ xp2,
    f16* __restrict__ hbuf)
{
  __shared__ float plds[2][4][4][16][20];   // [t&1][wave][jtile][row][col+pad] = 40 KB
  const int tid = threadIdx.x;
  const int l   = tid & 63;
  const int w   = tid >> 6;
  const int bid = blockIdx.x;        // 0..63
  const int xcd = bid & 7;
  const int g    = xcd >> 1;                       // batch group 0..3
  const int slot = ((bid >> 3) << 1) | (xcd & 1);  // j-slice 0..15
  const int c     = l & 15;
  const int brow0 = (l >> 4) << 2;                 // batch-row base
  const int j0    = slot * NJ + w * 16;            // wave's epilogue j-tile

  // W fragments: wf[jt][kt] row j = slot*64 + jt*16 + c,
  //              k = w*256 + kt*32 + (l>>4)*8 + e   -> 128 regs, pinned
  half8 wf[4][8];
  {
    const f16* wp = whh2 + (size_t)(slot * NJ + c) * H_DIM + w * 256 + ((l >> 4) << 3);
#pragma unroll
    for (int jt = 0; jt < 4; ++jt)
#pragma unroll
      for (int kt = 0; kt < 8; ++kt)
        wf[jt][kt] = *(const half8*)(wp + (size_t)jt * 16 * H_DIM + kt * 32);
#pragma unroll
    for (int jt = 0; jt < 4; ++jt)
#pragma unroll
      for (int kt = 0; kt < 8; ++kt)
        asm volatile("" : "+v"(wf[jt][kt]));      // keep resident (r4-proven: fits)
  }

  f16* gbase = hbuf + (size_t)g * (RING * MB * H_DIM);
  // per-lane spin-load base: row c, k-quarter w, chunk (l>>4)
  const uint frag_off = (uint)c * (H_DIM * 2) + (uint)w * 512 + ((uint)(l >> 4) << 4);

  // xp values: xq = current step (loaded one step ago)
  float xq0, xq1, xq2, xq3;
  {
    const f16* xb = xp2 + ((size_t)(g * MB + brow0)) * H_DIM + (j0 + c);
    xq0 = (float)xb[0];
    xq1 = (float)xb[H_DIM];
    xq2 = (float)xb[2 * H_DIM];
    xq3 = (float)xb[3 * H_DIM];
  }

  uint32x4 sv[8];   // spin/probe registers; live across the iteration boundary

  for (int t = 0; t < NSEQ; ++t) {
    if (t > 0) {
      // probe for slot t was pre-issued at the end of step t-1
      const char* sb = (const char*)gbase
                     + (size_t)(t & (RING - 1)) * (MB * H_DIM * 2) + frag_off;
      const uint pex = ((t >> 2) & 1) ? 0x00010001u : 0u;
      for (;;) {
        // full drain before EVERY check (r8-proven; no counted waits)
        asm volatile("s_waitcnt vmcnt(0)" ::: "memory");
        __builtin_amdgcn_sched_barrier(0);
        uint a = 0xFFFFFFFFu, o = 0u;
#pragma unroll
        for (int kt = 0; kt < 8; ++kt) {
          a &= sv[kt][0] & sv[kt][1] & sv[kt][2] & sv[kt][3];
          o |= sv[kt][0] | sv[kt][1] | sv[kt][2] | sv[kt][3];
        }
        uint bad = pex ? (~a & 0x00010001u) : (o & 0x00010001u);
        if (!__any((int)(bad != 0u))) break;
        // stale -> reissue the batch (all its loads retired above)
#pragma unroll
        for (int kt = 0; kt < 8; ++kt)
          asm volatile("global_load_dwordx4 %0, %1, off offset:%2 sc0 sc1"
                       : "=&v"(sv[kt]) : "v"(sb), "i"(kt * 64) : "memory");
      }
    }

    // prefetch xp for t+1 (plain C; cannot hoist above the "memory" asm; used
    // a full step later, so its HBM latency never hits the spin's waits)
    const int tn = (t + 1 < NSEQ) ? (t + 1) : (NSEQ - 1);
    const f16* xb = xp2 + ((size_t)tn * NBATCH + g * MB + brow0) * H_DIM + (j0 + c);
    float xn0 = (float)xb[0];
    float xn1 = (float)xb[H_DIM];
    float xn2 = (float)xb[2 * H_DIM];
    float xn3 = (float)xb[3 * H_DIM];

    f32x4_t acc[4];
#pragma unroll
    for (int jt = 0; jt < 4; ++jt) { acc[jt][0]=0.f; acc[jt][1]=0.f; acc[jt][2]=0.f; acc[jt][3]=0.f; }
    if (t > 0) {
      // partial h_t @ W^T over this wave's k-quarter: 4 j-chains of depth 8
#pragma unroll
      for (int kt = 0; kt < 8; ++kt) {
        half8 af = __builtin_bit_cast(half8, sv[kt]);
        acc[0] = __builtin_amdgcn_mfma_f32_16x16x32_f16(af, wf[0][kt], acc[0], 0, 0, 0);
        acc[1] = __builtin_amdgcn_mfma_f32_16x16x32_f16(af, wf[1][kt], acc[1], 0, 0, 0);
        acc[2] = __builtin_amdgcn_mfma_f32_16x16x32_f16(af, wf[2][kt], acc[2], 0, 0, 0);
        acc[3] = __builtin_amdgcn_mfma_f32_16x16x32_f16(af, wf[3][kt], acc[3], 0, 0, 0);
      }
    }
    // t == 0: h0 = 0 -> partials zero; h1 = tanh(xp_0)

    // cross-wave K-reduction via double-buffered padded LDS (2-way free access)
    const int tb = t & 1;
#pragma unroll
    for (int jt = 0; jt < 4; ++jt)
#pragma unroll
      for (int i = 0; i < 4; ++i)
        plds[tb][w][jt][brow0 + i][c] = acc[jt][i];
    __syncthreads();

    const uint pnew = (((t + 1) >> 2) & 1) ? 1u : 0u;
    uint* nb = (uint*)((char*)gbase + (size_t)((t + 1) & (RING - 1)) * (MB * H_DIM * 2));
    const float xr[4] = {xq0, xq1, xq2, xq3};
    uint st[4];
#pragma unroll
    for (int i = 0; i < 4; ++i) {
      float s = plds[tb][0][w][brow0 + i][c] + plds[tb][1][w][brow0 + i][c]
              + plds[tb][2][w][brow0 + i][c] + plds[tb][3][w][brow0 + i][c];
      float pre = s + xr[i];
      float e = __expf(2.0f * pre);
      float th = 1.0f - 2.0f / (e + 1.0f);
      f16 hf = (f16)th;
      uint hb = (uint)__builtin_bit_cast(unsigned short, hf);
      hb = (hb & 0xFFFEu) | pnew;
      uint pv = __shfl_xor(hb, 1, 64);
      st[i] = hb | (pv << 16);           // valid on even-c lanes: cols (c, c+1)
    }
    if ((c & 1) == 0) {
#pragma unroll
      for (int i = 0; i < 4; ++i) {
        uint idx = (uint)(brow0 + i) * (H_DIM / 2) + (uint)((j0 + c) >> 1);
        __hip_atomic_store(nb + idx, st[i], __ATOMIC_RELAXED, __HIP_MEMORY_SCOPE_AGENT);
      }
    }

    // pre-issue the probe for step t+1 (sv is dead here; drains at next spin's
    // vmcnt(0)). Overlaps one probe RTT with the loop tail + peer store landing.
    if (t + 1 < NSEQ) {
      const char* sbn = (const char*)gbase
                      + (size_t)((t + 1) & (RING - 1)) * (MB * H_DIM * 2) + frag_off;
#pragma unroll
      for (int kt = 0; kt < 8; ++kt)
        asm volatile("global_load_dwordx4 %0, %1, off offset:%2 sc0 sc1"
                     : "=&v"(sv[kt]) : "v"(sbn), "i"(kt * 64) : "memory");
    }

    // rotate xp pipeline (compiler inserts the wait here; loads are ~0.5us old)
    xq0 = xn0; xq1 = xn1; xq2 = xn2; xq3 = xn3;
    // no drain, no flag: consumers validate the data itself
  }
}

// ---------------- out = h_final @ W_fc^T + b_fc ----------------
__global__ __launch_bounds__(64) void fc_out_k(
    const f16* __restrict__ hbuf, const f16* __restrict__ wfc2,
    const float* __restrict__ bfc, float* __restrict__ out)
{
  const int l = threadIdx.x;
  const int wg = blockIdx.x;            // 0..127
  const int m0 = wg & 3;                // batch group (16-aligned b tile)
  const int n0 = (wg >> 2) << 4;        // output col base
  // h_512 lives in ring slot 512 % RING == 0
  const f16* ap = hbuf + (size_t)m0 * (RING * MB * H_DIM)
                  + (size_t)(l & 15) * H_DIM + ((l >> 4) << 3);
  const f16* bp = wfc2 + (size_t)(n0 + (l & 15)) * H_DIM + ((l >> 4) << 3);
  f32x4_t acc;
  float bv = bfc[n0 + (l & 15)];
  acc[0] = bv; acc[1] = bv; acc[2] = bv; acc[3] = bv;
#pragma unroll
  for (int kt = 0; kt < 32; ++kt) {
    half8 a = *(const half8*)(ap + kt * 32);
    half8 b = *(const half8*)(bp + kt * 32);
    acc = __builtin_amdgcn_mfma_f32_16x16x32_f16(a, b, acc, 0, 0, 0);
  }
  const int b0 = (m0 << 4) + ((l >> 4) << 2);
  const int o  = n0 + (l & 15);
#pragma unroll
  for (int i = 0; i < 4; ++i) out[(size_t)(b0 + i) * OUT_DIM + o] = acc[i];
}

// ---------------- launch ----------------
extern "C" void kernel_launch(void* const* d_in, const int* in_sizes, int n_in,
                              void* d_out, int out_size, void* d_ws, size_t ws_size,
                              hipStream_t stream) {
  const float* x   = (const float*)d_in[0];
  const float* wih = (const float*)d_in[1];
  const float* whh = (const float*)d_in[2];
  const float* bih = (const float*)d_in[3];
  const float* bhh = (const float*)d_in[4];
  const float* wfc = (const float*)d_in[5];
  const float* bfc = (const float*)d_in[6];
  float* out = (float*)d_out;
  char* ws = (char*)d_ws;

  // workspace layout (~67.6 MB total)
  f16*   xp2  = (f16*)(ws);                                  // 64 MB  [S][B][H] f16
  f16*   whh2 = (f16*)(ws + (size_t)(64 << 20));             // 2 MB
  f16*   wfc2 = (f16*)(ws + (size_t)(66 << 20));             // 1 MB
  float* bsum = (float*)(ws + (size_t)(67 << 20));           // 4 KB
  f16*   hbuf = (f16*)(ws + (size_t)(67 << 20) + 65536);     // 512 KB [4][RING=4][16][1024]

  // fill h ring with both-parity-invalid pattern (fresh every call)
  hipLaunchKernelGGL(fill_pat_k, dim3(128), dim3(256), 0, stream,
                     (uint32x4*)hbuf, (512 << 10) / 16);

  hipLaunchKernelGGL(cvt_f32_f16_k, dim3(1024), dim3(256), 0, stream, whh, whh2, H_DIM * H_DIM);
  hipLaunchKernelGGL(cvt_f32_f16_k, dim3(512),  dim3(256), 0, stream, wfc, wfc2, OUT_DIM * H_DIM);
  hipLaunchKernelGGL(bias_sum_k,    dim3(4),    dim3(256), 0, stream, bih, bhh, bsum);
  hipLaunchKernelGGL(xp_gemm_k,     dim3(256, 8), dim3(256), 0, stream, x, wih, bsum, xp2);
  hipLaunchKernelGGL(rnn_scan_k,    dim3(64),   dim3(256), 0, stream, whh2, xp2, hbuf);
  hipLaunchKernelGGL(fc_out_k,      dim3(128),  dim3(64),  0, stream, hbuf, wfc2, bfc, out);
}

// Round 12
// 1352.667 us; speedup vs baseline: 1.4547x; 1.4547x over previous
//
#include <hip/hip_runtime.h>
#include <hip/hip_fp16.h>

typedef _Float16 f16;
typedef _Float16 half8 __attribute__((ext_vector_type(8)));
typedef _Float16 half4 __attribute__((ext_vector_type(4)));
typedef float f32x4_t __attribute__((ext_vector_type(4)));
typedef unsigned int uint;
typedef unsigned int uint32x4 __attribute__((ext_vector_type(4)));

#define IN_DIM 512
#define H_DIM 1024
#define OUT_DIM 512
#define NBATCH 64
#define NSEQ 512
#define NGROUP 4
#define MB 16      // batch rows per group
#define WPG 16     // workgroups per group (j-split)
#define NJ 64      // j columns per workgroup
#define RING 4     // h ring depth (WG skew within a group <= 1 step)

// ---------------- f32 -> f16 conversion ----------------
__global__ __launch_bounds__(256) void cvt_f32_f16_k(const float* __restrict__ src,
                                                     f16* __restrict__ dst, int n) {
  int i = (blockIdx.x * 256 + threadIdx.x) * 4;
  if (i + 3 < n) {
    float4 v = *(const float4*)(src + i);
    half4 h;
    h[0] = (f16)v.x; h[1] = (f16)v.y; h[2] = (f16)v.z; h[3] = (f16)v.w;
    *(half4*)(dst + i) = h;
  }
}

__global__ __launch_bounds__(256) void bias_sum_k(const float* __restrict__ a,
                                                  const float* __restrict__ b,
                                                  float* __restrict__ o) {
  int i = blockIdx.x * 256 + threadIdx.x;
  if (i < H_DIM) o[i] = a[i] + b[i];
}

// fill hbuf ring with a pattern that is epoch-invalid for BOTH parities
// (low-half LSB=0, high-half LSB=1 -> never produced by real stores)
__global__ __launch_bounds__(256) void fill_pat_k(uint32x4* __restrict__ p, int n4) {
  int i = blockIdx.x * 256 + threadIdx.x;
  uint32x4 v;
  v[0] = 0x0001FFFEu; v[1] = 0x0001FFFEu; v[2] = 0x0001FFFEu; v[3] = 0x0001FFFEu;
  if (i < n4) p[i] = v;
}

// ---------------- xp = x @ W_ih^T + (b_ih + b_hh), stored [S][B][H] f16 ----------------
__global__ __launch_bounds__(256) void xp_gemm_k(
    const float* __restrict__ x, const float* __restrict__ wih,
    const float* __restrict__ bsum, f16* __restrict__ xp2)
{
  __shared__ f16 Alds[128 * 32];
  __shared__ f16 Blds[128 * 32];
  const int tid = threadIdx.x;
  const int l = tid & 63;
  const int w = tid >> 6;
  const int r0 = blockIdx.x * 128;
  const int n0 = blockIdx.y * 128;
  const int wm = (w >> 1) << 6;
  const int wn = (w & 1) << 6;
  const int srow = tid >> 1;
  const int scol = (tid & 1) << 4;
  const float* ax = x   + (size_t)(r0 + srow) * IN_DIM + scol;
  const float* bw = wih + (size_t)(n0 + srow) * IN_DIM + scol;
  const uint swz  = (uint)(srow & 7) << 4;
  const uint soff = (uint)srow * 64 + (uint)(tid & 1) * 32;
  char* Ab = (char*)Alds;
  char* Bb = (char*)Blds;

  f32x4_t acc[4][4];
  f32x4_t zv; zv[0] = 0.f; zv[1] = 0.f; zv[2] = 0.f; zv[3] = 0.f;
#pragma unroll
  for (int i = 0; i < 4; ++i)
#pragma unroll
    for (int j = 0; j < 4; ++j) acc[i][j] = zv;

  for (int k0 = 0; k0 < IN_DIM; k0 += 32) {
    float4 a0 = *(const float4*)(ax + k0);
    float4 a1 = *(const float4*)(ax + k0 + 4);
    float4 a2 = *(const float4*)(ax + k0 + 8);
    float4 a3 = *(const float4*)(ax + k0 + 12);
    float4 c0 = *(const float4*)(bw + k0);
    float4 c1 = *(const float4*)(bw + k0 + 4);
    float4 c2 = *(const float4*)(bw + k0 + 8);
    float4 c3 = *(const float4*)(bw + k0 + 12);
    __syncthreads();
    half8 pa0, pa1, pb0, pb1;
    pa0[0]=(f16)a0.x; pa0[1]=(f16)a0.y; pa0[2]=(f16)a0.z; pa0[3]=(f16)a0.w;
    pa0[4]=(f16)a1.x; pa0[5]=(f16)a1.y; pa0[6]=(f16)a1.z; pa0[7]=(f16)a1.w;
    pa1[0]=(f16)a2.x; pa1[1]=(f16)a2.y; pa1[2]=(f16)a2.z; pa1[3]=(f16)a2.w;
    pa1[4]=(f16)a3.x; pa1[5]=(f16)a3.y; pa1[6]=(f16)a3.z; pa1[7]=(f16)a3.w;
    pb0[0]=(f16)c0.x; pb0[1]=(f16)c0.y; pb0[2]=(f16)c0.z; pb0[3]=(f16)c0.w;
    pb0[4]=(f16)c1.x; pb0[5]=(f16)c1.y; pb0[6]=(f16)c1.z; pb0[7]=(f16)c1.w;
    pb1[0]=(f16)c2.x; pb1[1]=(f16)c2.y; pb1[2]=(f16)c2.z; pb1[3]=(f16)c2.w;
    pb1[4]=(f16)c3.x; pb1[5]=(f16)c3.y; pb1[6]=(f16)c3.z; pb1[7]=(f16)c3.w;
    *(half8*)(Ab + (soff ^ swz)) = pa0;
    *(half8*)(Ab + ((soff + 16) ^ swz)) = pa1;
    *(half8*)(Bb + (soff ^ swz)) = pb0;
    *(half8*)(Bb + ((soff + 16) ^ swz)) = pb1;
    __syncthreads();
    half8 af[4], bf[4];
#pragma unroll
    for (int mt = 0; mt < 4; ++mt) {
      uint rr = (uint)(wm + mt * 16 + (l & 15));
      uint off = rr * 64 + ((uint)(l >> 4) << 4);
      af[mt] = *(const half8*)(Ab + (off ^ ((rr & 7) << 4)));
    }
#pragma unroll
    for (int nt = 0; nt < 4; ++nt) {
      uint rr = (uint)(wn + nt * 16 + (l & 15));
      uint off = rr * 64 + ((uint)(l >> 4) << 4);
      bf[nt] = *(const half8*)(Bb + (off ^ ((rr & 7) << 4)));
    }
#pragma unroll
    for (int mt = 0; mt < 4; ++mt)
#pragma unroll
      for (int nt = 0; nt < 4; ++nt)
        acc[mt][nt] = __builtin_amdgcn_mfma_f32_16x16x32_f16(af[mt], bf[nt], acc[mt][nt], 0, 0, 0);
  }

#pragma unroll
  for (int nt = 0; nt < 4; ++nt) {
    const int n = n0 + wn + nt * 16 + (l & 15);
    const float bv = bsum[n];
#pragma unroll
    for (int mt = 0; mt < 4; ++mt) {
#pragma unroll
      for (int i = 0; i < 4; ++i) {
        int r = r0 + wm + mt * 16 + ((l >> 4) << 2) + i;
        int s = r & (NSEQ - 1);
        int b = r >> 9;
        xp2[((size_t)s * NBATCH + b) * H_DIM + n] = (f16)(acc[mt][nt][i] + bv);
      }
    }
  }
}

// ---------------- persistent recurrent scan (r8-proven protocol + xp-ahead) ----------------
// 64 WGs = 4 groups x 16 j-slices. K-split: wave w holds W[64j x 256k] f16 in
// 128 pinned regs, pulls its 512B h A-fragment per step from L3 (sc0 sc1).
// Data self-validates via per-f16 epoch LSB (parity of t>>2); producers store
// relaxed agent-atomics, never wait. Spin protocol: issue 8 -> vmcnt(0) ->
// check -> retry (the only asm pattern proven stable on this part).
//  (1) xp_{t+1} prefetched with plain C loads placed AFTER the spin asm
//      ("memory" clobber stops hoisting); consumed one step later, so the
//      cold-HBM xp read is off the spin's vmcnt(0) critical path. The rotate
//      executes BEFORE any new asm loads, so its compiler-inserted wait only
//      covers long-retired C loads (the r11 lesson).
//  (2) plds double-buffered by t&1 (closes the WAR window, no extra barrier).
__global__ __launch_bounds__(256, 1) void rnn_scan_k(
    const f16* __restrict__ whh2, const f16* __restrict__ xp2,
    f16* __restrict__ hbuf)
{
  __shared__ float plds[2][4][4][16][20];   // [t&1][wave][jtile][row][col+pad] = 40 KB
  const int tid = threadIdx.x;
  const int l   = tid & 63;
  const int w   = tid >> 6;
  const int bid = blockIdx.x;        // 0..63
  const int xcd = bid & 7;
  const int g    = xcd >> 1;                       // batch group 0..3
  const int slot = ((bid >> 3) << 1) | (xcd & 1);  // j-slice 0..15
  const int c     = l & 15;
  const int brow0 = (l >> 4) << 2;                 // batch-row base
  const int j0    = slot * NJ + w * 16;            // wave's epilogue j-tile

  // W fragments: wf[jt][kt] row j = slot*64 + jt*16 + c,
  //              k = w*256 + kt*32 + (l>>4)*8 + e   -> 128 regs, pinned
  half8 wf[4][8];
  {
    const f16* wp = whh2 + (size_t)(slot * NJ + c) * H_DIM + w * 256 + ((l >> 4) << 3);
#pragma unroll
    for (int jt = 0; jt < 4; ++jt)
#pragma unroll
      for (int kt = 0; kt < 8; ++kt)
        wf[jt][kt] = *(const half8*)(wp + (size_t)jt * 16 * H_DIM + kt * 32);
#pragma unroll
    for (int jt = 0; jt < 4; ++jt)
#pragma unroll
      for (int kt = 0; kt < 8; ++kt)
        asm volatile("" : "+v"(wf[jt][kt]));      // keep resident (r4-proven: fits)
  }

  f16* gbase = hbuf + (size_t)g * (RING * MB * H_DIM);
  // per-lane spin-load base: row c, k-quarter w, chunk (l>>4)
  const uint frag_off = (uint)c * (H_DIM * 2) + (uint)w * 512 + ((uint)(l >> 4) << 4);

  // xp values: xq = current step (loaded one step ago)
  float xq0, xq1, xq2, xq3;
  {
    const f16* xb = xp2 + ((size_t)(g * MB + brow0)) * H_DIM + (j0 + c);
    xq0 = (float)xb[0];
    xq1 = (float)xb[H_DIM];
    xq2 = (float)xb[2 * H_DIM];
    xq3 = (float)xb[3 * H_DIM];
  }

  for (int t = 0; t < NSEQ; ++t) {
    uint32x4 sv[8];
    if (t > 0) {
      const char* sb = (const char*)gbase
                     + (size_t)(t & (RING - 1)) * (MB * H_DIM * 2) + frag_off;
      const uint pex = ((t >> 2) & 1) ? 0x00010001u : 0u;
      // r8-verbatim spin: issue 8, drain, validate, retry
      for (;;) {
#pragma unroll
        for (int kt = 0; kt < 8; ++kt)
          asm volatile("global_load_dwordx4 %0, %1, off offset:%2 sc0 sc1"
                       : "=v"(sv[kt]) : "v"(sb), "i"(kt * 64) : "memory");
        asm volatile("s_waitcnt vmcnt(0)" ::: "memory");
        __builtin_amdgcn_sched_barrier(0);
        uint a = 0xFFFFFFFFu, o = 0u;
#pragma unroll
        for (int kt = 0; kt < 8; ++kt) {
          a &= sv[kt][0] & sv[kt][1] & sv[kt][2] & sv[kt][3];
          o |= sv[kt][0] | sv[kt][1] | sv[kt][2] | sv[kt][3];
        }
        uint bad = pex ? (~a & 0x00010001u) : (o & 0x00010001u);
        if (!bad || !__any((int)(bad != 0u))) break;
      }
    }

    // prefetch xp for t+1 (plain C; cannot hoist above the "memory" asm; used
    // a full step later, so its HBM latency never hits a vmcnt(0))
    const int tn = (t + 1 < NSEQ) ? (t + 1) : (NSEQ - 1);
    const f16* xb = xp2 + ((size_t)tn * NBATCH + g * MB + brow0) * H_DIM + (j0 + c);
    float xn0 = (float)xb[0];
    float xn1 = (float)xb[H_DIM];
    float xn2 = (float)xb[2 * H_DIM];
    float xn3 = (float)xb[3 * H_DIM];

    f32x4_t acc[4];
#pragma unroll
    for (int jt = 0; jt < 4; ++jt) { acc[jt][0]=0.f; acc[jt][1]=0.f; acc[jt][2]=0.f; acc[jt][3]=0.f; }
    if (t > 0) {
      // partial h_t @ W^T over this wave's k-quarter: 4 j-chains of depth 8
#pragma unroll
      for (int kt = 0; kt < 8; ++kt) {
        half8 af = __builtin_bit_cast(half8, sv[kt]);
        acc[0] = __builtin_amdgcn_mfma_f32_16x16x32_f16(af, wf[0][kt], acc[0], 0, 0, 0);
        acc[1] = __builtin_amdgcn_mfma_f32_16x16x32_f16(af, wf[1][kt], acc[1], 0, 0, 0);
        acc[2] = __builtin_amdgcn_mfma_f32_16x16x32_f16(af, wf[2][kt], acc[2], 0, 0, 0);
        acc[3] = __builtin_amdgcn_mfma_f32_16x16x32_f16(af, wf[3][kt], acc[3], 0, 0, 0);
      }
    }
    // t == 0: h0 = 0 -> partials zero; h1 = tanh(xp_0)

    // cross-wave K-reduction via double-buffered padded LDS (2-way free access)
    const int tb = t & 1;
#pragma unroll
    for (int jt = 0; jt < 4; ++jt)
#pragma unroll
      for (int i = 0; i < 4; ++i)
        plds[tb][w][jt][brow0 + i][c] = acc[jt][i];
    __syncthreads();

    const uint pnew = (((t + 1) >> 2) & 1) ? 1u : 0u;
    uint* nb = (uint*)((char*)gbase + (size_t)((t + 1) & (RING - 1)) * (MB * H_DIM * 2));
    const float xr[4] = {xq0, xq1, xq2, xq3};
    uint st[4];
#pragma unroll
    for (int i = 0; i < 4; ++i) {
      float s = plds[tb][0][w][brow0 + i][c] + plds[tb][1][w][brow0 + i][c]
              + plds[tb][2][w][brow0 + i][c] + plds[tb][3][w][brow0 + i][c];
      float pre = s + xr[i];
      float e = __expf(2.0f * pre);
      float th = 1.0f - 2.0f / (e + 1.0f);
      f16 hf = (f16)th;
      uint hb = (uint)__builtin_bit_cast(unsigned short, hf);
      hb = (hb & 0xFFFEu) | pnew;
      uint pv = __shfl_xor(hb, 1, 64);
      st[i] = hb | (pv << 16);           // valid on even-c lanes: cols (c, c+1)
    }
    if ((c & 1) == 0) {
#pragma unroll
      for (int i = 0; i < 4; ++i) {
        uint idx = (uint)(brow0 + i) * (H_DIM / 2) + (uint)((j0 + c) >> 1);
        __hip_atomic_store(nb + idx, st[i], __ATOMIC_RELAXED, __HIP_MEMORY_SCOPE_AGENT);
      }
    }
    // rotate xp pipeline (compiler inserts the wait here; loads are ~0.5us old)
    xq0 = xn0; xq1 = xn1; xq2 = xn2; xq3 = xn3;
    // no drain, no flag: consumers validate the data itself
  }
}

// ---------------- out = h_final @ W_fc^T + b_fc ----------------
__global__ __launch_bounds__(64) void fc_out_k(
    const f16* __restrict__ hbuf, const f16* __restrict__ wfc2,
    const float* __restrict__ bfc, float* __restrict__ out)
{
  const int l = threadIdx.x;
  const int wg = blockIdx.x;            // 0..127
  const int m0 = wg & 3;                // batch group (16-aligned b tile)
  const int n0 = (wg >> 2) << 4;        // output col base
  // h_512 lives in ring slot 512 % RING == 0
  const f16* ap = hbuf + (size_t)m0 * (RING * MB * H_DIM)
                  + (size_t)(l & 15) * H_DIM + ((l >> 4) << 3);
  const f16* bp = wfc2 + (size_t)(n0 + (l & 15)) * H_DIM + ((l >> 4) << 3);
  f32x4_t acc;
  float bv = bfc[n0 + (l & 15)];
  acc[0] = bv; acc[1] = bv; acc[2] = bv; acc[3] = bv;
#pragma unroll
  for (int kt = 0; kt < 32; ++kt) {
    half8 a = *(const half8*)(ap + kt * 32);
    half8 b = *(const half8*)(bp + kt * 32);
    acc = __builtin_amdgcn_mfma_f32_16x16x32_f16(a, b, acc, 0, 0, 0);
  }
  const int b0 = (m0 << 4) + ((l >> 4) << 2);
  const int o  = n0 + (l & 15);
#pragma unroll
  for (int i = 0; i < 4; ++i) out[(size_t)(b0 + i) * OUT_DIM + o] = acc[i];
}

// ---------------- launch ----------------
extern "C" void kernel_launch(void* const* d_in, const int* in_sizes, int n_in,
                              void* d_out, int out_size, void* d_ws, size_t ws_size,
                              hipStream_t stream) {
  const float* x   = (const float*)d_in[0];
  const float* wih = (const float*)d_in[1];
  const float* whh = (const float*)d_in[2];
  const float* bih = (const float*)d_in[3];
  const float* bhh = (const float*)d_in[4];
  const float* wfc = (const float*)d_in[5];
  const float* bfc = (const float*)d_in[6];
  float* out = (float*)d_out;
  char* ws = (char*)d_ws;

  // workspace layout (~67.6 MB total)
  f16*   xp2  = (f16*)(ws);                                  // 64 MB  [S][B][H] f16
  f16*   whh2 = (f16*)(ws + (size_t)(64 << 20));             // 2 MB
  f16*   wfc2 = (f16*)(ws + (size_t)(66 << 20));             // 1 MB
  float* bsum = (float*)(ws + (size_t)(67 << 20));           // 4 KB
  f16*   hbuf = (f16*)(ws + (size_t)(67 << 20) + 65536);     // 512 KB [4][RING=4][16][1024]

  // fill h ring with both-parity-invalid pattern (fresh every call)
  hipLaunchKernelGGL(fill_pat_k, dim3(128), dim3(256), 0, stream,
                     (uint32x4*)hbuf, (512 << 10) / 16);

  hipLaunchKernelGGL(cvt_f32_f16_k, dim3(1024), dim3(256), 0, stream, whh, whh2, H_DIM * H_DIM);
  hipLaunchKernelGGL(cvt_f32_f16_k, dim3(512),  dim3(256), 0, stream, wfc, wfc2, OUT_DIM * H_DIM);
  hipLaunchKernelGGL(bias_sum_k,    dim3(4),    dim3(256), 0, stream, bih, bhh, bsum);
  hipLaunchKernelGGL(xp_gemm_k,     dim3(256, 8), dim3(256), 0, stream, x, wih, bsum, xp2);
  hipLaunchKernelGGL(rnn_scan_k,    dim3(64),   dim3(256), 0, stream, whh2, xp2, hbuf);
  hipLaunchKernelGGL(fc_out_k,      dim3(128),  dim3(64),  0, stream, hbuf, wfc2, bfc, out);
}